// Round 10
// baseline (431.133 us; speedup 1.0000x reference)
//
#include <hip/hip_runtime.h>

typedef _Float16 half8 __attribute__((ext_vector_type(8)));
typedef float floatx4 __attribute__((ext_vector_type(4)));
typedef unsigned uint4v __attribute__((ext_vector_type(4)));

#define Bsz 512
#define Tsz 168
#define Fsz 16
#define Hsz 256
#define KTILES 9      // K = 288 = 9 * 32  (256 h + 16 x + 16 zero pad)
#define LDS_K 296     // padded LDS row stride in halves

// workspace layout (bytes, all 16B aligned)
#define WSW_OFF   0          // swizzled [w_hh|w_ih|0] f16 frags: 64nt*9kt*64lane*16B = 589824
#define BIAS_OFF  589824     // reordered (b_ih+b_hh) fp32: 1024*4 = 4096
#define HH_OFF    675840     // h history f16 [B][T][H]: 512*168*256*2 = 44040192
#define XBUF_OFF  (HH_OFF + 44040192)   // tagged exchange ring: 32bb*2*16m*128slot*8B = 1 MB

// ---------------- prep: lstm weight swizzle + bias (f16 frag table) --------
__global__ __launch_bounds__(256) void k_prep(
    const float* __restrict__ w_hh, const float* __restrict__ w_ih,
    const float* __restrict__ b_ih, const float* __restrict__ b_hh,
    _Float16* __restrict__ wsw, float* __restrict__ bias) {
    const int b = blockIdx.x, tid = threadIdx.x;
    const int lane = tid & 63, sub = tid >> 6;
    if (b < 144) {                         // w_hh|w_ih swizzle: 576 tiles
        int tile = b * 4 + sub;            // nt*9 + kt
        int nt = tile / KTILES, kt = tile - nt * KTILES;
        int n_in = lane & 15, kg = lane >> 4;
        int J = nt >> 2, g = nt & 3;
        int n_orig = g * 256 + J * 16 + n_in;
        half8 v;
#pragma unroll
        for (int e = 0; e < 8; ++e) {
            int k = kt * 32 + kg * 8 + e;
            float f;
            if (k < 256)      f = w_hh[n_orig * 256 + k];
            else if (k < 272) f = w_ih[n_orig * 16 + (k - 256)];
            else              f = 0.0f;
            v[e] = (_Float16)f;
        }
        ((half8*)wsw)[tile * 64 + lane] = v;
    } else {                               // bias reorder: 1024
        int id = (b - 144) * 256 + tid;
        int nt = id >> 4, n = id & 15;
        int J = nt >> 2, g = nt & 3;
        int n_orig = g * 256 + J * 16 + n;
        bias[id] = b_ih[n_orig] + b_hh[n_orig];
    }
}

// ---------------- recurrent LSTM v21: v14 champion + targeted barriers -----
// v14 = 342us. Its G1/G4 __syncthreads each emit s_waitcnt vmcnt(0) before
// s_barrier (HIP semantics), forcing the AGENT-SCOPE PUBLISH STORE-ACK
// (MALL RT ~400-800cy) and NT-store ack to drain INSIDE every step — pure
// waste: partner consumption is enforced by their poll spin, and ring-slot
// reuse at t+2 is transitively ordered through the poll chain (publish t+2
// requires poll t+1 requires partner publish t+1 requires partner poll t).
// v21 replaces G1/G4 with {s_waitcnt lgkmcnt(0); s_barrier; sched_barrier}
// (HipKittens pattern; rule #18 fence against post-barrier LDS-read hoist).
// LDS writes are the only thing that must be visible across the barrier.
// Body otherwise byte-identical to the measured champion.
#define WG_BARRIER()                                          \
    do {                                                      \
        asm volatile("s_waitcnt lgkmcnt(0)" ::: "memory");    \
        __builtin_amdgcn_s_barrier();                         \
        __builtin_amdgcn_sched_barrier(0);                    \
    } while (0)

__global__ __launch_bounds__(512, 1) void k_lstm21(
    const float* __restrict__ x, const _Float16* __restrict__ wsw,
    const float* __restrict__ bias, unsigned* __restrict__ hh32,
    unsigned long long* __restrict__ xbuf) {
    __shared__ __align__(16) _Float16 h_lds[16][LDS_K];   // h | x | pad
    __shared__ float glds[4][16][68];                     // [gate][m][j_local], pad 68

    const int tid = threadIdx.x;
    const int wave = tid >> 6, lane = tid & 63;
    const int n_in = lane & 15, quad = lane >> 4;
    const int bb = blockIdx.x & 31, ng = blockIdx.x >> 5;   // XCD-colocated swizzle
    const int b0 = bb * 16;
    const int Jl = wave & 3;               // local J-block 0..3
    const int gp = wave >> 2;              // gate pair: 0 -> (i,f), 1 -> (g,o)

    // ---- one-time: this wave's 18 weight B-frags straight into VGPRs ----
    float bs[2];
    half8 wf[2][KTILES];
#pragma unroll
    for (int gg = 0; gg < 2; ++gg) {
        const int nt = ng * 16 + Jl * 4 + gp * 2 + gg;
        bs[gg] = bias[nt * 16 + n_in];
#pragma unroll
        for (int kt = 0; kt < KTILES; ++kt)
            wf[gg][kt] = ((const half8*)wsw)[((size_t)nt * KTILES + kt) * 64 + lane];
    }

    // zero h0 + x + pad, stage x_0 (prologue: full __syncthreads is fine)
    for (int i = tid; i < 16 * LDS_K; i += 512)
        ((_Float16*)h_lds)[i] = (_Float16)0.0f;
    __syncthreads();
    if (tid < 256) {
        int m = tid >> 4, f = tid & 15;
        h_lds[m][Hsz + f] = (_Float16)x[((b0 + m) * Tsz + 0) * Fsz + f];
    }
    __syncthreads();

    // cell/publish/gather ownership: thread -> (m = tid>>5, slot = tid&31)
    const int cm = tid >> 5, cj = tid & 31;
    float c_st[2] = {0.f, 0.f};

    for (int t = 0; t < Tsz; ++t) {
        // ---- A-frags from LDS; B-frags all from registers ----
        half8 afr[KTILES];
#pragma unroll
        for (int kt = 0; kt < KTILES; ++kt)
            afr[kt] = *(const half8*)&h_lds[n_in][kt * 32 + quad * 8];

        floatx4 acc[2] = {(floatx4){0.f,0.f,0.f,0.f}, (floatx4){0.f,0.f,0.f,0.f}};
#pragma unroll
        for (int gg = 0; gg < 2; ++gg) {
#pragma unroll
            for (int kt = 0; kt < KTILES; ++kt)
                acc[gg] = __builtin_amdgcn_mfma_f32_16x16x32_f16(afr[kt], wf[gg][kt], acc[gg], 0, 0, 0);
        }

        // ---- stage gate pre-activations to LDS ----
#pragma unroll
        for (int gg = 0; gg < 2; ++gg)
#pragma unroll
            for (int r = 0; r < 4; ++r)
                glds[gp * 2 + gg][quad * 4 + r][Jl * 16 + n_in] = acc[gg][r] + bs[gg];
        WG_BARRIER();   // G1: gates staged (LDS only); afr reads done -> h_lds writable

        // ---- cell update: thread owns (cm, j_local = 2cj, 2cj+1) ----
        union { _Float16 f[2]; unsigned u; } pk;
#pragma unroll
        for (int e = 0; e < 2; ++e) {
            int jl = 2 * cj + e;
            float ig = glds[0][cm][jl];
            float fg = glds[1][cm][jl];
            float gg_ = glds[2][cm][jl];
            float og = glds[3][cm][jl];
            float si = 1.0f / (1.0f + __expf(-ig));
            float sf = 1.0f / (1.0f + __expf(-fg));
            float tg = 1.0f - 2.0f / (__expf(2.0f * gg_) + 1.0f);
            float so = 1.0f / (1.0f + __expf(-og));
            float c = sf * c_st[e] + si * tg;
            c_st[e] = c;
            float th = 1.0f - 2.0f / (__expf(2.0f * c) + 1.0f);
            pk.f[e] = (_Float16)(so * th);
        }
        // own quarter of h_{t+1} straight into LDS (safe: reads done at G1)
        *(unsigned*)&h_lds[cm][ng * 64 + 2 * cj] = pk.u;

        const size_t rb = ((size_t)((bb * 2 + (t & 1)) * 16));   // ring base (rows)
        if (t + 1 < Tsz) {
            // publish own slot as a single tagged atom {data | t+1} (L2-resident)
            unsigned long long pv = ((unsigned long long)pk.u << 32) | (unsigned)(t + 1);
            __hip_atomic_store(&xbuf[(rb + cm) * 128 + ng * 32 + cj], pv,
                               __ATOMIC_RELAXED, __HIP_MEMORY_SCOPE_AGENT);
        }
        // history write for k_mlp: NON-TEMPORAL -> no L2 allocate, xbuf survives
        __builtin_nontemporal_store(
            pk.u, &hh32[((size_t)(b0 + cm) * Tsz + t) * 128 + ng * 32 + cj]);

        if (t + 1 < Tsz) {
            // prefetch x_{t+1}; ack overlaps the polls below
            float xr = 0.0f;
            if (tid < 256)
                xr = x[((b0 + (tid >> 4)) * Tsz + (t + 1)) * Fsz + (tid & 15)];

            // ---- gather 3 partner quarters: CONCURRENT tagged-atom polls ----
            const unsigned want = (unsigned)(t + 1);
            unsigned long long* p1 = &xbuf[(rb + cm) * 128 + ((ng + 1) & 3) * 32 + cj];
            unsigned long long* p2 = &xbuf[(rb + cm) * 128 + ((ng + 2) & 3) * 32 + cj];
            unsigned long long* p3 = &xbuf[(rb + cm) * 128 + ((ng + 3) & 3) * 32 + cj];
            unsigned long long v1 = __hip_atomic_load(p1, __ATOMIC_RELAXED,
                                                      __HIP_MEMORY_SCOPE_AGENT);
            unsigned long long v2 = __hip_atomic_load(p2, __ATOMIC_RELAXED,
                                                      __HIP_MEMORY_SCOPE_AGENT);
            unsigned long long v3 = __hip_atomic_load(p3, __ATOMIC_RELAXED,
                                                      __HIP_MEMORY_SCOPE_AGENT);
            while ((unsigned)v1 != want || (unsigned)v2 != want || (unsigned)v3 != want) {
                if ((unsigned)v1 != want)
                    v1 = __hip_atomic_load(p1, __ATOMIC_RELAXED, __HIP_MEMORY_SCOPE_AGENT);
                if ((unsigned)v2 != want)
                    v2 = __hip_atomic_load(p2, __ATOMIC_RELAXED, __HIP_MEMORY_SCOPE_AGENT);
                if ((unsigned)v3 != want)
                    v3 = __hip_atomic_load(p3, __ATOMIC_RELAXED, __HIP_MEMORY_SCOPE_AGENT);
            }
            *(unsigned*)&h_lds[cm][((ng + 1) & 3) * 64 + 2 * cj] = (unsigned)(v1 >> 32);
            *(unsigned*)&h_lds[cm][((ng + 2) & 3) * 64 + 2 * cj] = (unsigned)(v2 >> 32);
            *(unsigned*)&h_lds[cm][((ng + 3) & 3) * 64 + 2 * cj] = (unsigned)(v3 >> 32);
            if (tid < 256)
                h_lds[tid >> 4][Hsz + (tid & 15)] = (_Float16)xr;
            WG_BARRIER();   // G4: h_{t+1}+x_{t+1} staged (LDS only; store-acks float)
        }
    }
}

// ---------------- MLP head v7: peeled 3-chunk, normal hh loads -------------
// (R9: NT->normal was neutral; keep — no downside, simpler cache behavior)
__global__ __launch_bounds__(512, 2) void k_mlp7(
    const _Float16* __restrict__ hh, const float* __restrict__ fc1_w,
    const float* __restrict__ fc2_w, const float* __restrict__ b1,
    const float* __restrict__ b2, const float* __restrict__ w3,
    const float* __restrict__ b3, float* __restrict__ out) {
    __shared__ __align__(16) _Float16 w1sh[64 * 512];   // 64 KB
    __shared__ __align__(16) _Float16 w2sh[16 * 512];   // 16 KB
    __shared__ _Float16 st1[8][16][136];
    __shared__ _Float16 st2[8][16][72];

    const int tid = threadIdx.x;
    const int wave = tid >> 6, lane = tid & 63;
    const int n_in = lane & 15, quad = lane >> 4;

    {   // build fragment tables directly from fc1_w/fc2_w
#pragma unroll
        for (int it = 0; it < 8; ++it) {
            int s = it * 512 + tid;            // s = tile*64 + ln
            int tile = s >> 6, ln = s & 63;
            int nt = tile >> 3, kt = tile & 7, ni = ln & 15, kg = ln >> 4;
            const float* src = &fc1_w[(nt * 16 + ni) * 256 + kt * 32 + kg * 8];
            half8 v;
#pragma unroll
            for (int e = 0; e < 8; ++e) v[e] = (_Float16)src[e];
            ((half8*)w1sh)[s] = v;
        }
#pragma unroll
        for (int it = 0; it < 2; ++it) {
            int s = it * 512 + tid;
            int tile = s >> 6, ln = s & 63;
            int nt = tile >> 2, kt = tile & 3, ni = ln & 15, kg = ln >> 4;
            const float* src = &fc2_w[(nt * 16 + ni) * 128 + kt * 32 + kg * 8];
            half8 v;
#pragma unroll
            for (int e = 0; e < 8; ++e) v[e] = (_Float16)src[e];
            ((half8*)w2sh)[s] = v;
        }
    }
    __syncthreads();

    uint4v bufA[8], bufB[8], bufC[8];
    const int ch0 = blockIdx.x, ch1 = blockIdx.x + 224, ch2 = blockIdx.x + 448;

#define MLP_LOAD(dst, ch)                                                      \
    {                                                                          \
        const int tok0_ = (ch) * 128 + wave * 16;                              \
        _Pragma("unroll")                                                      \
        for (int kt = 0; kt < 8; ++kt)                                         \
            dst[kt] = *(const uint4v*)&hh[(size_t)(tok0_ + n_in) * 256 +       \
                                          kt * 32 + quad * 8];                 \
    }

    MLP_LOAD(bufA, ch0)
    MLP_LOAD(bufB, ch1)
    MLP_LOAD(bufC, ch2)

    auto compute = [&](const uint4v* raw, int chunk) {
        const int tok0 = chunk * 128 + wave * 16;
        half8 afr[8];
#pragma unroll
        for (int kt = 0; kt < 8; ++kt)
            afr[kt] = __builtin_bit_cast(half8, raw[kt]);

#pragma unroll
        for (int nt = 0; nt < 8; ++nt) {
            floatx4 a = (floatx4){0.f, 0.f, 0.f, 0.f};
#pragma unroll
            for (int kt = 0; kt < 8; ++kt) {
                half8 bfr = *(const half8*)&w1sh[(nt * 8 + kt) * 512 + lane * 8];
                a = __builtin_amdgcn_mfma_f32_16x16x32_f16(afr[kt], bfr, a, 0, 0, 0);
            }
            float bbv = b1[nt * 16 + n_in];
#pragma unroll
            for (int r = 0; r < 4; ++r) {
                float v = a[r] + bbv;
                st1[wave][quad * 4 + r][nt * 16 + n_in] = (_Float16)(v > 0.f ? v : 0.f);
            }
        }

        half8 a2[4];
#pragma unroll
        for (int kt = 0; kt < 4; ++kt)
            a2[kt] = *(const half8*)&st1[wave][n_in][kt * 32 + quad * 8];
#pragma unroll
        for (int nt = 0; nt < 4; ++nt) {
            floatx4 a = (floatx4){0.f, 0.f, 0.f, 0.f};
#pragma unroll
            for (int kt = 0; kt < 4; ++kt) {
                half8 bfr = *(const half8*)&w2sh[(nt * 4 + kt) * 512 + lane * 8];
                a = __builtin_amdgcn_mfma_f32_16x16x32_f16(a2[kt], bfr, a, 0, 0, 0);
            }
            float bbv = b2[nt * 16 + n_in];
#pragma unroll
            for (int r = 0; r < 4; ++r) {
                float v = a[r] + bbv;
                st2[wave][quad * 4 + r][nt * 16 + n_in] = (_Float16)(v > 0.f ? v : 0.f);
            }
        }

        float p = 0.0f;
#pragma unroll
        for (int e = 0; e < 16; ++e)
            p += (float)st2[wave][n_in][quad * 16 + e] * w3[quad * 16 + e];
        p += __shfl_down(p, 32);
        p += __shfl_down(p, 16);
        if (quad == 0) out[tok0 + n_in] = p + b3[0];
    };

    compute(bufA, ch0);
    compute(bufB, ch1);
    compute(bufC, ch2);
#undef MLP_LOAD
}

extern "C" void kernel_launch(void* const* d_in, const int* in_sizes, int n_in,
                              void* d_out, int out_size, void* d_ws, size_t ws_size,
                              hipStream_t stream) {
    const float* x     = (const float*)d_in[0];
    const float* w_ih  = (const float*)d_in[1];
    const float* w_hh  = (const float*)d_in[2];
    const float* b_ih  = (const float*)d_in[3];
    const float* b_hh  = (const float*)d_in[4];
    const float* fc1_w = (const float*)d_in[5];
    const float* fc1_b = (const float*)d_in[6];
    const float* fc2_w = (const float*)d_in[7];
    const float* fc2_b = (const float*)d_in[8];
    const float* fc3_w = (const float*)d_in[9];
    const float* fc3_b = (const float*)d_in[10];

    char* ws = (char*)d_ws;
    _Float16* wsw  = (_Float16*)(ws + WSW_OFF);
    float*    bias = (float*)(ws + BIAS_OFF);
    _Float16* hhist= (_Float16*)(ws + HH_OFF);
    unsigned long long* xbuf = (unsigned long long*)(ws + XBUF_OFF);

    k_prep<<<148, 256, 0, stream>>>(w_hh, w_ih, b_ih, b_hh, wsw, bias);
    k_lstm21<<<128, 512, 0, stream>>>(x, wsw, bias, (unsigned*)hhist, xbuf);
    k_mlp7<<<224, 512, 0, stream>>>(hhist, fc1_w, fc2_w, fc1_b, fc2_b,
                                    fc3_w, fc3_b, (float*)d_out);
}